// Round 8
// baseline (144.100 us; speedup 1.0000x reference)
//
#include <hip/hip_runtime.h>
#include <cstdint>
#include <cstddef>

#define KCAT  384
#define NPB   16      // nodes per fused block
#define AST   264     // LDS panel row stride elems (528B): [x(128) | mean(128)] + pad
#define CH    96      // edges per async chunk (96 rows x 256B = 24KB)
#define KMAXB 512     // max edges per block (16 nodes x deg<=32)
#define VP_BLOCKS 24

typedef __attribute__((ext_vector_type(8))) short bf16x8;
typedef __attribute__((ext_vector_type(4))) float f32x4;

static __device__ __forceinline__ unsigned short f2bf(float f) {
    unsigned int u = __builtin_bit_cast(unsigned int, f);
    u += 0x7fffu + ((u >> 16) & 1u);
    return (unsigned short)(u >> 16);
}
static __device__ __forceinline__ float bfhi(unsigned int u) { return __builtin_bit_cast(float, u & 0xFFFF0000u); }
static __device__ __forceinline__ float bflo(unsigned int u) { return __builtin_bit_cast(float, u << 16); }
static __device__ __forceinline__ void acc8(float* a, const uint4& v) {
    a[0] += bflo(v.x); a[1] += bfhi(v.x); a[2] += bflo(v.y); a[3] += bfhi(v.y);
    a[4] += bflo(v.z); a[5] += bfhi(v.z); a[6] += bflo(v.w); a[7] += bfhi(v.w);
}
// async global->LDS, 16B/lane; LDS side = wave-uniform base + lane*16; gptr is PER-LANE
static __device__ __forceinline__ void async16(const unsigned short* g, void* lds_wave_base) {
    __builtin_amdgcn_global_load_lds(
        (const __attribute__((address_space(1))) void*)g,
        (__attribute__((address_space(3))) void*)lds_wave_base,
        16, 0, 0);
}

// ---------------- Prep: Vp pack (GEMM B layout), xb = bf16(x), blkoff[0..nblk] ----------------
// Vp: element ((g*12 + s)*64 + lane)*8 + j = W[g*16 + (lane&15)][s*32 + (lane>>4)*8 + j]
__global__ __launch_bounds__(256)
void prep(const float* __restrict__ x, const float* __restrict__ Wg,
          const float* __restrict__ Wl, const float* __restrict__ Ws,
          const int* __restrict__ dst, unsigned short* __restrict__ Vp,
          unsigned short* __restrict__ xb, int* __restrict__ blkoff,
          int total8, int nblk1, int noffb, int E) {
    const int bx = blockIdx.x, t = threadIdx.x;
    if (bx < VP_BLOCKS) {
        int gid = bx * 256 + t;
        if (gid < 6144) {
            int l = gid & 63, srow = (gid >> 6) % 12, g = gid / 768;
            int o = g * 16 + (l & 15);
            int k = srow * 32 + (l >> 4) * 8;
            const float* w; int kk;
            if (k < 128)      { w = Wg; kk = k; }
            else if (k < 256) { w = Wl; kk = k - 128; }
            else              { w = Ws; kk = k - 256; }
            const float* p = w + o * 128 + kk;
            uint4 u;
            u.x = (unsigned)f2bf(p[0]) | ((unsigned)f2bf(p[1]) << 16);
            u.y = (unsigned)f2bf(p[2]) | ((unsigned)f2bf(p[3]) << 16);
            u.z = (unsigned)f2bf(p[4]) | ((unsigned)f2bf(p[5]) << 16);
            u.w = (unsigned)f2bf(p[6]) | ((unsigned)f2bf(p[7]) << 16);
            ((uint4*)Vp)[gid] = u;
        }
    } else if (bx < VP_BLOCKS + noffb) {
        int b = (bx - VP_BLOCKS) * 256 + t;
        if (b < nblk1) {                       // nblk+1 entries: blkoff[nblk] = E
            int target = b * NPB;
            int lo = 0, hi = E;
            while (lo < hi) { int mid = (lo + hi) >> 1; if (dst[mid] < target) lo = mid + 1; else hi = mid; }
            blkoff[b] = lo;
        }
    } else {
        int gid = (bx - VP_BLOCKS - noffb) * 256 + t;
        if (gid < total8) {
            const float4* px = (const float4*)x + (size_t)gid * 2;
            float4 a = px[0], bq = px[1];
            uint4 u;
            u.x = (unsigned)f2bf(a.x)  | ((unsigned)f2bf(a.y)  << 16);
            u.y = (unsigned)f2bf(a.z)  | ((unsigned)f2bf(a.w)  << 16);
            u.z = (unsigned)f2bf(bq.x) | ((unsigned)f2bf(bq.y) << 16);
            u.w = (unsigned)f2bf(bq.z) | ((unsigned)f2bf(bq.w) << 16);
            ((uint4*)xb)[gid] = u;
        }
    }
}

// ---------------- Fused: async-LDS gather -> per-thread reduce -> MFMA -> ELU ----------------
// 256 threads = 4 waves, 16 nodes/block, 3125 blocks, ~35KB LDS -> 4 blocks/CU.
// Gather: per 96-edge chunk each wave issues 6 global_load_lds (per-lane scattered
// global addrs, 4 rows/instr) -> zero VGPR data buffers, vmcnt-deep pipeline.
// Reduce: thread (node=t>>4, col=swizzled 16B group) sums its node's chunk edges
// from LDS; accumulators persist across chunks; no cross-lane reduction.
__global__ __launch_bounds__(256, 4)
void fused(const unsigned short* __restrict__ xb, const int* __restrict__ src,
           const int* __restrict__ deg, const int* __restrict__ blkoff,
           const unsigned short* __restrict__ Vp, const float* __restrict__ bias,
           float* __restrict__ out, int N) {
    __shared__ __align__(16) unsigned short Ebuf[CH * 128];   // 24576 B edge rows
    __shared__ __align__(16) unsigned short As[NPB * AST];    // 8448 B panel
    __shared__ int sarr[KMAXB];                               // 2048 B src window
    __shared__ int sstart[NPB];
    __shared__ int sdegs[NPB];
    __shared__ unsigned smask[NPB];
    const int t = threadIdx.x, wv = t >> 6, lane = t & 63;
    const int base = blockIdx.x * NPB;
    const int blk0 = blkoff[blockIdx.x];
    const int Kblk = blkoff[blockIdx.x + 1] - blk0;

    if (wv == 0) {       // per-node deg + local start offsets (exclusive scan over 16)
        int dg = 0;
        if (lane < NPB && base + lane < N) dg = deg[base + lane];
        int incl = dg;
#pragma unroll
        for (int off = 1; off < NPB; off <<= 1) {
            int v = __shfl_up(incl, off, 64);
            if (lane >= off) incl += v;
        }
        if (lane < NPB) { sstart[lane] = incl - dg; sdegs[lane] = dg; smask[lane] = dg > 0 ? ~0u : 0u; }
    }
    for (int k = t; k < Kblk; k += 256) sarr[k] = src[blk0 + k];   // stage src window
    {   // stage panel x rows (L2-hot, 4KB)
        int i = t >> 4, cg = t & 15;
        int grow = base + i; if (grow > N - 1) grow = N - 1;
        uint4 xv = *((const uint4*)(xb + (size_t)grow * 128 + cg * 8));
        *(uint4*)(As + i * AST + cg * 8) = xv;
    }
    __syncthreads();

    const int node = t >> 4;
    const int cg   = ((t & 15) + node) & 15;       // bank-swizzled 16B column
    const int sloc = sstart[node], dnode = sdegs[node];
    float acc[8] = {0,0,0,0,0,0,0,0};
    const int nch = (Kblk + CH - 1) / CH;

    for (int ch = 0; ch < nch; ++ch) {
        if (ch) __syncthreads();                   // prev reduce done before overwrite
        const int C0 = ch * CH;
        // issue async gathers: instr i covers local edges C0 + i*16 + wv*4 + (lane>>4)
#pragma unroll
        for (int i = 0; i < CH / 16; ++i) {
            int ebase = i * 16 + wv * 4;
            if (C0 + ebase < Kblk) {               // wave-uniform guard
                int le = C0 + ebase + (lane >> 4);
                if (le > Kblk - 1) le = Kblk - 1;  // per-lane clamp (dup-safe)
                int sidx = sarr[le];
                async16(xb + (size_t)sidx * 128 + (lane & 15) * 8,
                        (char*)Ebuf + (size_t)ebase * 256);
            }
        }
        __syncthreads();                           // drains vmcnt -> Ebuf valid
        int lo = sloc > C0 ? sloc : C0;
        int hi = sloc + dnode, ce = C0 + CH; if (hi > ce) hi = ce;
        int e = lo;
        for (; e + 1 < hi; e += 2) {
            uint4 v0 = *(const uint4*)(Ebuf + (size_t)(e - C0) * 128 + cg * 8);
            uint4 v1 = *(const uint4*)(Ebuf + (size_t)(e + 1 - C0) * 128 + cg * 8);
            acc8(acc, v0); acc8(acc, v1);
        }
        if (e < hi) {
            uint4 v0 = *(const uint4*)(Ebuf + (size_t)(e - C0) * 128 + cg * 8);
            acc8(acc, v0);
        }
    }
    {   // mean -> panel (bf16)
        float inv = (dnode > 0) ? 1.0f / (float)dnode : 0.0f;
        uint4 u;
        u.x = (unsigned)f2bf(acc[0]*inv) | ((unsigned)f2bf(acc[1]*inv) << 16);
        u.y = (unsigned)f2bf(acc[2]*inv) | ((unsigned)f2bf(acc[3]*inv) << 16);
        u.z = (unsigned)f2bf(acc[4]*inv) | ((unsigned)f2bf(acc[5]*inv) << 16);
        u.w = (unsigned)f2bf(acc[6]*inv) | ((unsigned)f2bf(acc[7]*inv) << 16);
        *(uint4*)(As + node * AST + 128 + cg * 8) = u;
    }
    __syncthreads();

    // ---- GEMM phase: wave wv -> col-groups 2wv, 2wv+1; 12 k-steps; B prefetch from Vp
    const int c = lane & 15, quad = lane >> 4;
    const unsigned msk = smask[c];
    const int g0 = 2 * wv, g1 = 2 * wv + 1;
    const bf16x8* VB = (const bf16x8*)Vp;
    f32x4 acc0 = (f32x4){0.f, 0.f, 0.f, 0.f};
    f32x4 acc1 = (f32x4){0.f, 0.f, 0.f, 0.f};
    bf16x8 b0 = VB[(g0 * 12) * 64 + lane];
    bf16x8 b1 = VB[(g1 * 12) * 64 + lane];
#pragma unroll
    for (int s = 0; s < 12; ++s) {
        int sn = (s + 1 < 12) ? s + 1 : 0;
        bf16x8 n0 = VB[(g0 * 12 + sn) * 64 + lane];
        bf16x8 n1 = VB[(g1 * 12 + sn) * 64 + lane];
        int seg = s >> 2, kk = (s & 3) * 32;
        bf16x8 afr = *(const bf16x8*)(As + c * AST + (seg == 1 ? 128 : 0) + kk + quad * 8);
        if (seg == 2) {                            // mask.x segment
            uint4 ai = __builtin_bit_cast(uint4, afr);
            ai.x &= msk; ai.y &= msk; ai.z &= msk; ai.w &= msk;
            afr = __builtin_bit_cast(bf16x8, ai);
        }
        acc0 = __builtin_amdgcn_mfma_f32_16x16x32_bf16(afr, b0, acc0, 0, 0, 0);
        acc1 = __builtin_amdgcn_mfma_f32_16x16x32_bf16(afr, b1, acc1, 0, 0, 0);
        b0 = n0; b1 = n1;
    }

    // epilogue: + bias, ELU, store. C/D: col=lane&15, row=quad*4+reg
    const int col0 = g0 * 16 + c, col1 = g1 * 16 + c;
    const float bv0 = bias[col0], bv1 = bias[col1];
#pragma unroll
    for (int reg = 0; reg < 4; ++reg) {
        int grow = base + quad * 4 + reg;
        if (grow < N) {
            float v0 = acc0[reg] + bv0;
            float v1 = acc1[reg] + bv1;
            out[(size_t)grow * 128 + col0] = (v0 > 0.f) ? v0 : __expf(v0) - 1.0f;
            out[(size_t)grow * 128 + col1] = (v1 > 0.f) ? v1 : __expf(v1) - 1.0f;
        }
    }
}

extern "C" void kernel_launch(void* const* d_in, const int* in_sizes, int n_in,
                              void* d_out, int out_size, void* d_ws, size_t ws_size,
                              hipStream_t stream) {
    const float* x  = (const float*)d_in[0];
    const float* Wg = (const float*)d_in[1];
    const float* Wl = (const float*)d_in[2];
    const float* Ws = (const float*)d_in[3];
    const float* b  = (const float*)d_in[4];
    const int*   src = (const int*)d_in[5];
    const int*   dst = (const int*)d_in[6];
    const int*   deg = (const int*)d_in[7];
    const int E = in_sizes[5];
    const int N = in_sizes[7];
    float* out = (float*)d_out;

    unsigned short* Vp     = (unsigned short*)d_ws;              // 96 KB (packed B)
    int*            blkoff = (int*)((char*)d_ws + 98304);        // 32 KB reserved
    unsigned short* xb     = (unsigned short*)((char*)d_ws + 131072);  // 12.8 MB

    const int nblk   = (N + NPB - 1) / NPB;        // 3125
    const int nblk1  = nblk + 1;                   // sentinel entry = E
    const int noffb  = (nblk1 + 255) / 256;        // 13
    const int total8 = N * 16;
    const int nconv  = (total8 + 255) / 256;       // 3125

    prep<<<dim3(VP_BLOCKS + noffb + nconv), dim3(256), 0, stream>>>(
        x, Wg, Wl, Ws, dst, Vp, xb, blkoff, total8, nblk1, noffb, E);
    fused<<<dim3(nblk), dim3(256), 0, stream>>>(xb, src, deg, blkoff, Vp, b, out, N);
}